// Round 18
// baseline (279.113 us; speedup 1.0000x reference)
//
#include <hip/hip_runtime.h>
#include <hip/hip_bf16.h>

typedef __attribute__((ext_vector_type(8))) short short8_t;
typedef __attribute__((ext_vector_type(4))) float f32x4;
typedef float f32x4u __attribute__((ext_vector_type(4), aligned(4)));  // 4B-aligned vector load

#define NNODES 50000
#define FIN 1433
#define HID 128
#define NCLS 7
#define KT1 45          // ceil(1433/32)
#define BK 32
#define BM 32           // rows per block (full-K slab in LDS)
#define ROWSTR 1448     // A LDS row stride in ushorts (1440 + 8 pad -> 2-way only)
#define CAP 96          // fixed CSR slots/node; Poisson(32) => P(deg>96) ~ 0; exact via ovf

static __device__ __forceinline__ unsigned short f2bf(float f) {
    union { float f; unsigned int u; } v; v.f = f;
    unsigned int u = v.u;
    u += 0x7FFFu + ((u >> 16) & 1u);   // round-to-nearest-even
    return (unsigned short)(u >> 16);
}
static __device__ __forceinline__ float u2f(unsigned int u) {
    union { unsigned int u; float f; } v; v.u = u; return v.f;
}

// ---------------- W1 pack: W1[FIN][HID] f32 -> W1s[KT1][512 segs][8 bf16]
// seg = g*128 + c (g = k-octet within BK=32 tile, c = col); zero-padded k>=FIN.
__global__ void prep_w1(const float* __restrict__ W1, unsigned short* __restrict__ W1s) {
    int tid = blockIdx.x * 512 + threadIdx.x;
    if (tid >= KT1 * 512) return;
    int kt = tid >> 9, seg = tid & 511;
    int c = seg & 127, g = seg >> 7;
    int kb = kt * BK + g * 8;
    unsigned int w[4];
    #pragma unroll
    for (int p = 0; p < 4; ++p) {
        int k0 = kb + p * 2, k1 = kb + p * 2 + 1;
        unsigned short lo = (k0 < FIN) ? f2bf(W1[(size_t)k0 * HID + c]) : (unsigned short)0;
        unsigned short hi = (k1 < FIN) ? f2bf(W1[(size_t)k1 * HID + c]) : (unsigned short)0;
        w[p] = (unsigned int)lo | ((unsigned int)hi << 16);
    }
    uint4* dstp = (uint4*)(W1s + (size_t)tid * 8);
    uint4 val; val.x = w[0]; val.y = w[1]; val.z = w[2]; val.w = w[3];
    *dstp = val;
}

// ---------------- FAT kernel: gemm blocks [0,gb) || FILL blocks [gb, grid) ---
// GEMM (barrier-free K-loop): stage A[32 rows][full K] bf16 into LDS ONCE
// (92KB, padded stride), sync once, then 16 waves each own one 16x16 output
// tile and sweep K=45 MFMA steps with NO barriers: A-frag = ds_read_b128
// (base + kt*64B imm), B-frag = direct global from L2-hot W1s (368KB).
// Compiler is free to software-pipeline; acc = 4 VGPR/lane.
// FILL: fixed-stride CSR scatter (1024t x 8 edges).
__global__ __launch_bounds__(1024) void gemm_fill(const float* __restrict__ x,
                                                  const unsigned short* __restrict__ W1s,
                                                  unsigned short* __restrict__ h, int M,
                                                  const int* __restrict__ src,
                                                  const int* __restrict__ dst, int E,
                                                  int* __restrict__ cnt,
                                                  int* __restrict__ csr_f,
                                                  int* __restrict__ ovf_cnt,
                                                  int2* __restrict__ ovf, int gb) {
    __shared__ unsigned short As[BM * ROWSTR];   // 92,672 B

    if (blockIdx.x >= gb) {
        // ---- fill blocks: 1024 threads x 8 edges ----
        int bid = blockIdx.x - gb;
        int i = (bid * 1024 + (int)threadIdx.x) * 8;
        int lim = min(i + 8, E);
        for (int e = i; e < lim; ++e) {
            int d = dst[e], s = src[e];
            int pos = atomicAdd(&cnt[d], 1);
            if (pos < CAP) csr_f[d * CAP + pos] = s;
            else { int op = atomicAdd(ovf_cnt, 1); ovf[op] = make_int2(d, s); }
        }
        return;
    }

    // ---- gemm blocks ----
    const int t = threadIdx.x;
    const int rowBase = blockIdx.x * BM;

    // stage A: 32 rows x 360 f32-quads -> bf16 LDS (once)
    for (int j = t; j < BM * 360; j += 1024) {
        int row = j / 360, q = j - row * 360;
        int k = q * 4;
        int gr = min(rowBase + row, M - 1);
        float4 v;
        if (k + 3 < FIN) {
            f32x4u vv = *(const f32x4u*)(x + (size_t)gr * FIN + k);
            v.x = vv.x; v.y = vv.y; v.z = vv.z; v.w = vv.w;
        } else {
            const float* p = x + (size_t)gr * FIN;
            v.x = (k + 0 < FIN) ? p[k + 0] : 0.f;
            v.y = (k + 1 < FIN) ? p[k + 1] : 0.f;
            v.z = (k + 2 < FIN) ? p[k + 2] : 0.f;
            v.w = (k + 3 < FIN) ? p[k + 3] : 0.f;
        }
        __hip_bfloat162 lo2 = __float22bfloat162_rn(make_float2(v.x, v.y));
        __hip_bfloat162 hi2 = __float22bfloat162_rn(make_float2(v.z, v.w));
        unsigned int ulo, uhi;
        __builtin_memcpy(&ulo, &lo2, 4);
        __builtin_memcpy(&uhi, &hi2, 4);
        unsigned long long pk = ((unsigned long long)uhi << 32) | (unsigned long long)ulo;
        *(unsigned long long*)(&As[row * ROWSTR + k]) = pk;
    }
    __syncthreads();   // the ONLY barrier

    // compute: wave w -> rowtile (w&1), coltile (w>>1); one 16x16 tile each
    const int wave = t >> 6, lane = t & 63;
    const int rowt = wave & 1, colt = wave >> 1;
    const int r = lane & 15, u = lane >> 4;
    const unsigned short* As_base = As + (rowt * 16 + r) * ROWSTR + u * 8;
    const unsigned short* bp = W1s + ((size_t)(u * 128 + colt * 16 + r)) * 8;
    f32x4 acc = {};
    #pragma unroll 5
    for (int kt = 0; kt < KT1; ++kt) {
        short8_t a = *(const short8_t*)(As_base + kt * 32);
        short8_t b = *(const short8_t*)(bp + (size_t)kt * 4096);
        acc = __builtin_amdgcn_mfma_f32_16x16x32_bf16(a, b, acc, 0, 0, 0);
    }

    // epilogue: C layout col=lane&15, row=(lane>>4)*4+reg
    #pragma unroll
    for (int reg = 0; reg < 4; ++reg) {
        int grow = rowBase + rowt * 16 + u * 4 + reg;
        if (grow < M) {
            int gcol = colt * 16 + r;
            h[(size_t)grow * HID + gcol] = f2bf(acc[reg]);
        }
    }
}

// ---------------- self-loop insert + dinv (one thread per node) --------------
__global__ void self_dinv(int* __restrict__ cnt, int* __restrict__ csr_f,
                          float* __restrict__ dinv,
                          int* __restrict__ ovf_cnt, int2* __restrict__ ovf, int n) {
    int i = blockIdx.x * 256 + threadIdx.x;
    if (i >= n) return;
    int c = cnt[i];
    if (c < CAP) csr_f[i * CAP + c] = i;
    else { int op = atomicAdd(ovf_cnt, 1); ovf[op] = make_int2(i, i); }
    cnt[i] = c + 1;
    dinv[i] = rsqrtf((float)(c + 1));
}

// ---------------- Aggregation 1 + bias + relu + @W2 fused ----------------
__global__ __launch_bounds__(256) void agg1(const unsigned short* __restrict__ h,
                                            const int* __restrict__ cnt,
                                            const int* __restrict__ csr_f,
                                            const float* __restrict__ dinv,
                                            const float* __restrict__ b1,
                                            const float* __restrict__ W2,
                                            const int* __restrict__ ovf_cnt,
                                            const int2* __restrict__ ovf,
                                            float* __restrict__ h2s, int n) {
    __shared__ float W2s[HID * NCLS];
    for (int i = threadIdx.x; i < HID * NCLS; i += 256) W2s[i] = W2[i];
    __syncthreads();
    int wave = threadIdx.x >> 6, lane = threadIdx.x & 63;
    int v = blockIdx.x * 4 + wave;
    if (v >= n) return;
    const int fr = lane & 15, g = lane >> 4;
    int total = cnt[v];
    int inrow = min(total, CAP);
    const int base = v * CAP;
    float acc[8] = {};
    #pragma unroll 4
    for (int j = g; j < inrow; j += 4) {
        int s = csr_f[base + j];
        float ds = dinv[s];
        uint4 q = *(const uint4*)(h + (size_t)s * HID + fr * 8);
        unsigned int w[4] = {q.x, q.y, q.z, q.w};
        #pragma unroll
        for (int p = 0; p < 4; ++p) {
            acc[p * 2 + 0] += ds * u2f(w[p] << 16);          // low bf16
            acc[p * 2 + 1] += ds * u2f(w[p] & 0xffff0000u);  // high bf16
        }
    }
    if (__builtin_expect(total > CAP, 0) && g == 0) {
        int on = *ovf_cnt;
        for (int k = 0; k < on; ++k) {
            int2 pr = ovf[k];
            if (pr.x == v) {
                int s = pr.y;
                float ds = dinv[s];
                uint4 q = *(const uint4*)(h + (size_t)s * HID + fr * 8);
                unsigned int w[4] = {q.x, q.y, q.z, q.w};
                #pragma unroll
                for (int p = 0; p < 4; ++p) {
                    acc[p * 2 + 0] += ds * u2f(w[p] << 16);
                    acc[p * 2 + 1] += ds * u2f(w[p] & 0xffff0000u);
                }
            }
        }
    }
    #pragma unroll
    for (int e = 0; e < 8; ++e) {
        acc[e] += __shfl_xor(acc[e], 16, 64);
        acc[e] += __shfl_xor(acc[e], 32, 64);
    }
    float dv = dinv[v];
    float p[NCLS];
    #pragma unroll
    for (int c = 0; c < NCLS; ++c) p[c] = 0.f;
    #pragma unroll
    for (int e = 0; e < 8; ++e) {
        int f = fr * 8 + e;
        float val = fmaxf(dv * acc[e] + b1[f], 0.f);
        #pragma unroll
        for (int c = 0; c < NCLS; ++c) p[c] += val * W2s[f * NCLS + c];
    }
    #pragma unroll
    for (int off = 8; off >= 1; off >>= 1)
        #pragma unroll
        for (int c = 0; c < NCLS; ++c)
            p[c] += __shfl_xor(p[c], off, 64);
    if (lane == 0) {
        #pragma unroll
        for (int c = 0; c < NCLS; ++c) h2s[(size_t)v * 8 + c] = dv * p[c];  // pre-scaled
        h2s[(size_t)v * 8 + 7] = 0.f;
    }
}

// ---------------- Aggregation 2 + bias ----------------
__global__ __launch_bounds__(256) void agg2(const float* __restrict__ h2s,
                                            const int* __restrict__ cnt,
                                            const int* __restrict__ csr_f,
                                            const float* __restrict__ dinv,
                                            const float* __restrict__ b2,
                                            const int* __restrict__ ovf_cnt,
                                            const int2* __restrict__ ovf,
                                            float* __restrict__ out, int n) {
    int wave = threadIdx.x >> 6, lane = threadIdx.x & 63;
    int half = lane >> 5;
    int c = lane & 7, g = (lane >> 3) & 3;
    int v = blockIdx.x * 8 + wave * 2 + half;
    if (v >= n) return;
    int total = cnt[v];
    int inrow = min(total, CAP);
    const int base = v * CAP;
    float acc = 0.f;
    #pragma unroll 4
    for (int j = g; j < inrow; j += 4) {
        int s = csr_f[base + j];
        acc += h2s[(size_t)s * 8 + c];
    }
    if (__builtin_expect(total > CAP, 0) && g == 0) {
        int on = *ovf_cnt;
        for (int k = 0; k < on; ++k) {
            int2 pr = ovf[k];
            if (pr.x == v) acc += h2s[(size_t)pr.y * 8 + c];
        }
    }
    acc += __shfl_xor(acc, 8, 64);
    acc += __shfl_xor(acc, 16, 64);
    if (g == 0 && c < NCLS) out[(size_t)v * NCLS + c] = dinv[v] * acc + b2[c];
}

extern "C" void kernel_launch(void* const* d_in, const int* in_sizes, int n_in,
                              void* d_out, int out_size, void* d_ws, size_t ws_size,
                              hipStream_t stream) {
    const float* x  = (const float*)d_in[0];
    const int*   ei = (const int*)d_in[1];    // int64 in reference but JAX x64-off => int32
    const float* W1 = (const float*)d_in[2];
    const float* b1 = (const float*)d_in[3];
    const float* W2 = (const float*)d_in[4];
    const float* b2 = (const float*)d_in[5];
    float* out = (float*)d_out;

    const int N = NNODES;
    const int E = in_sizes[1] / 2;
    const int* src = ei;
    const int* dst = ei + E;
    const int GB = (N + BM - 1) / BM;         // gemm blocks (1563)
    const int FB = (E + 8191) / 8192;         // fill blocks (1024t x 8 edges)

    char* ws = (char*)d_ws;
    size_t off = 0;
    auto alloc = [&](size_t bytes) {
        void* p = ws + off;
        off += (bytes + 255) & ~(size_t)255;
        return p;
    };
    int*   cnt     = (int*)alloc((size_t)N * 4);
    int*   ovf_cnt = (int*)alloc(4);
    float* dinv    = (float*)alloc((size_t)N * 4);
    int*   csr_f   = (int*)alloc((size_t)N * CAP * 4);
    int2*  ovf     = (int2*)alloc((size_t)4096 * 8);
    unsigned short* W1s = (unsigned short*)alloc((size_t)KT1 * 512 * 8 * 2);
    unsigned short* h   = (unsigned short*)alloc((size_t)N * HID * 2);
    float* h2s     = (float*)alloc((size_t)N * 8 * 4);

    // zero cnt + ovf_cnt (contiguous allocations)
    hipMemsetAsync(cnt, 0, ((char*)ovf_cnt - (char*)cnt) + 256, stream);
    prep_w1<<<(KT1 * 512 + 511) / 512, 512, 0, stream>>>(W1, W1s);
    gemm_fill<<<GB + FB, 1024, 0, stream>>>(x, W1s, h, N, src, dst, E,
                                            cnt, csr_f, ovf_cnt, ovf, GB);
    self_dinv<<<(N + 255) / 256, 256, 0, stream>>>(cnt, csr_f, dinv, ovf_cnt, ovf, N);
    agg1<<<(N + 3) / 4, 256, 0, stream>>>(h, cnt, csr_f, dinv, b1, W2, ovf_cnt, ovf, h2s, N);
    agg2<<<(N + 7) / 8, 256, 0, stream>>>(h2s, cnt, csr_f, dinv, b2, ovf_cnt, ovf, out, N);
}

// Round 20
// 244.737 us; speedup vs baseline: 1.1405x; 1.1405x over previous
//
#include <hip/hip_runtime.h>
#include <hip/hip_bf16.h>

typedef __attribute__((ext_vector_type(8))) short short8_t;
typedef __attribute__((ext_vector_type(4))) float f32x4;
typedef float f32x4u __attribute__((ext_vector_type(4), aligned(4)));  // 4B-aligned vector load
typedef int i32x4 __attribute__((ext_vector_type(4)));                 // clang vec (NT-load ok)

#define NNODES 50000
#define FIN 1433
#define HID 128
#define NCLS 7
#define KT1 45          // ceil(1433/32)
#define BK 32
#define BM 128
#define CAP 96          // fixed CSR slots/node; Poisson(32) => P(deg>96) ~ 0; exact via ovf
#define GSTR 1040       // A LDS g-stride in ushorts (128*8 + 16 pad -> conflict-free)

static __device__ __forceinline__ unsigned short f2bf(float f) {
    union { float f; unsigned int u; } v; v.f = f;
    unsigned int u = v.u;
    u += 0x7FFFu + ((u >> 16) & 1u);   // round-to-nearest-even
    return (unsigned short)(u >> 16);
}
static __device__ __forceinline__ float u2f(unsigned int u) {
    union { unsigned int u; float f; } v; v.u = u; return v.f;
}

// ---------------- W1 pack: W1[FIN][HID] f32 -> W1s[KT1][512 segs][8 bf16]
__global__ void prep_w1(const float* __restrict__ W1, unsigned short* __restrict__ W1s) {
    int tid = blockIdx.x * 512 + threadIdx.x;
    if (tid >= KT1 * 512) return;
    int kt = tid >> 9, seg = tid & 511;
    int c = seg & 127, g = seg >> 7;
    int kb = kt * BK + g * 8;
    unsigned int w[4];
    #pragma unroll
    for (int p = 0; p < 4; ++p) {
        int k0 = kb + p * 2, k1 = kb + p * 2 + 1;
        unsigned short lo = (k0 < FIN) ? f2bf(W1[(size_t)k0 * HID + c]) : (unsigned short)0;
        unsigned short hi = (k1 < FIN) ? f2bf(W1[(size_t)k1 * HID + c]) : (unsigned short)0;
        w[p] = (unsigned int)lo | ((unsigned int)hi << 16);
    }
    uint4* dstp = (uint4*)(W1s + (size_t)tid * 8);
    uint4 val; val.x = w[0]; val.y = w[1]; val.z = w[2]; val.w = w[3];
    *dstp = val;
}

// ---------------- FAT kernel: gemm blocks [0,gb) || FILL blocks [gb, grid) ---
// GEMM: BM=128, BK=32, 512t, 41KB LDS -> 3 blocks/CU, plain __syncthreads()
// per K-iter (R17 structure, best known). FILL: fixed-stride CSR scatter with
// NONTEMPORAL edge loads + csr stores (keep single-use streams out of L2 so
// gemm's W1s/x staging keeps the cache).
__global__ __launch_bounds__(512) void gemm_fill(const float* __restrict__ x,
                                                 const unsigned short* __restrict__ W1s,
                                                 unsigned short* __restrict__ h, int M,
                                                 const int* __restrict__ src,
                                                 const int* __restrict__ dst, int E,
                                                 int* __restrict__ cnt,
                                                 int* __restrict__ csr_f,
                                                 int* __restrict__ ovf_cnt,
                                                 int2* __restrict__ ovf, int gb) {
    __shared__ unsigned short As[2][4160];   // [g^(row&3)][row][8], GSTR=1040
    __shared__ unsigned short Bs[3][4096];   // [g 4][c 128][8] linear (gload_lds)

    if (blockIdx.x >= gb) {
        // ---- fill blocks: 512 threads x 8 edges, NT streams ----
        int bid = blockIdx.x - gb;
        int i = (bid * 512 + (int)threadIdx.x) * 8;
        if (i + 7 < E) {
            i32x4 d0 = __builtin_nontemporal_load((const i32x4*)(dst + i));
            i32x4 d1 = __builtin_nontemporal_load((const i32x4*)(dst + i + 4));
            i32x4 s0 = __builtin_nontemporal_load((const i32x4*)(src + i));
            i32x4 s1 = __builtin_nontemporal_load((const i32x4*)(src + i + 4));
            int dd[8] = {d0.x, d0.y, d0.z, d0.w, d1.x, d1.y, d1.z, d1.w};
            int ss[8] = {s0.x, s0.y, s0.z, s0.w, s1.x, s1.y, s1.z, s1.w};
            #pragma unroll
            for (int e = 0; e < 8; ++e) {
                int pos = atomicAdd(&cnt[dd[e]], 1);
                if (pos < CAP) __builtin_nontemporal_store(ss[e], &csr_f[dd[e] * CAP + pos]);
                else { int op = atomicAdd(ovf_cnt, 1); ovf[op] = make_int2(dd[e], ss[e]); }
            }
        } else if (i < E) {
            for (int e = i; e < E; ++e) {
                int d = dst[e], s = src[e];
                int pos = atomicAdd(&cnt[d], 1);
                if (pos < CAP) csr_f[d * CAP + pos] = s;
                else { int op = atomicAdd(ovf_cnt, 1); ovf[op] = make_int2(d, s); }
            }
        }
        return;
    }

    // ---- gemm blocks ----
    const int t = threadIdx.x;
    const int wave = t >> 6, lane = t & 63;
    const int wm = wave >> 1, wn = wave & 1;
    const int r = lane & 15, u = lane >> 4;       // u in 0..3 = K-octet & row-quad
    const int rowBase = blockIdx.x * BM;
    f32x4 acc[2][4] = {};

    float4 areg[2];

    auto issueA = [&](int kt) {
        int k0 = kt * BK;
        #pragma unroll
        for (int i = 0; i < 2; ++i) {
            int quad = i * 512 + t;
            int row = quad >> 3, kq = quad & 7;
            int gr = min(rowBase + row, M - 1);   // clamp; OOB rows unstored
            int gk = k0 + kq * 4;                 // in-bounds for kt <= 43
            f32x4u v = *(const f32x4u*)(x + (size_t)gr * FIN + gk);
            areg[i].x = v.x; areg[i].y = v.y; areg[i].z = v.z; areg[i].w = v.w;
        }
    };
    auto issueA_tail = [&]() {                    // kt=44: k 1408..1439, guard FIN
        #pragma unroll
        for (int i = 0; i < 2; ++i) {
            int quad = i * 512 + t;
            int row = quad >> 3, kq = quad & 7;
            int gr = min(rowBase + row, M - 1);
            int gk = 1408 + kq * 4;
            const float* p = x + (size_t)gr * FIN;
            areg[i].x = (gk + 0 < FIN) ? p[gk + 0] : 0.f;
            areg[i].y = (gk + 1 < FIN) ? p[gk + 1] : 0.f;
            areg[i].z = (gk + 2 < FIN) ? p[gk + 2] : 0.f;
            areg[i].w = (gk + 3 < FIN) ? p[gk + 3] : 0.f;
        }
    };
    auto issueB = [&](int kt, int buf) {
        const unsigned short* gp = W1s + ((size_t)kt * 512 + t) * 8;
        unsigned short* lp = &Bs[buf][(wave * 64) * 8];
        __builtin_amdgcn_global_load_lds(
            (const __attribute__((address_space(1))) unsigned int*)gp,
            (__attribute__((address_space(3))) unsigned int*)lp, 16, 0, 0);
    };
    auto writeA = [&](int buf) {
        #pragma unroll
        for (int i = 0; i < 2; ++i) {
            int quad = i * 512 + t;
            int row = quad >> 3, kq = quad & 7;
            __hip_bfloat162 lo2 = __float22bfloat162_rn(make_float2(areg[i].x, areg[i].y));
            __hip_bfloat162 hi2 = __float22bfloat162_rn(make_float2(areg[i].z, areg[i].w));
            unsigned int ulo, uhi;
            __builtin_memcpy(&ulo, &lo2, 4);
            __builtin_memcpy(&uhi, &hi2, 4);
            unsigned long long pk = ((unsigned long long)uhi << 32) | (unsigned long long)ulo;
            int g = kq >> 1, half = kq & 1;
            int us = ((g ^ (row & 3)) * GSTR) + row * 8 + half * 4;
            *(unsigned long long*)(&As[buf][us]) = pk;
        }
    };
    auto compute = [&](int kt) {
        const int abuf = kt & 1, bbuf = kt % 3;
        short8_t af[2], bfr[4];
        #pragma unroll
        for (int mi = 0; mi < 2; ++mi) {
            int row = wm * 32 + mi * 16 + r;
            int us = ((u ^ (row & 3)) * GSTR) + row * 8;
            af[mi] = *(const short8_t*)(&As[abuf][us]);
        }
        #pragma unroll
        for (int ni = 0; ni < 4; ++ni) {
            int c = wn * 64 + ni * 16 + r;
            bfr[ni] = *(const short8_t*)(&Bs[bbuf][u * 1024 + c * 8]);
        }
        #pragma unroll
        for (int mi = 0; mi < 2; ++mi)
            #pragma unroll
            for (int ni = 0; ni < 4; ++ni)
                acc[mi][ni] = __builtin_amdgcn_mfma_f32_16x16x32_bf16(af[mi], bfr[ni], acc[mi][ni], 0, 0, 0);
    };

    // prologue: tile 0 staged; tile 1 in flight
    issueA(0); issueB(0, 0);
    writeA(0);                       // implicit wait on A(0)
    issueA(1); issueB(1, 1);
    __syncthreads();                 // drains B(0); A(1)/B(1) complete too

    // main loop: kt = 0..41 (issues up to tile 43; tiles 0..43 all k-in-bounds)
    for (int kt = 0; kt < KT1 - 3; ++kt) {
        compute(kt);
        writeA((kt + 1) & 1);        // A(t+1) loads landed by prev barrier
        issueA(kt + 2);
        issueB(kt + 2, (kt + 2) % 3);
        __syncthreads();             // one barrier/iter; 3-block TLP hides drain
    }
    // kt = 42
    {
        compute(KT1 - 3);            // 42
        writeA((KT1 - 2) & 1);       // A(43) -> As[1]
        __syncthreads();
    }
    // stage guarded tail tile 44
    issueA_tail();
    issueB(KT1 - 1, (KT1 - 1) % 3);  // B(44) -> Bs[2]
    writeA((KT1 - 1) & 1);           // A(44) -> As[0]
    __syncthreads();
    compute(KT1 - 2);                // 43
    compute(KT1 - 1);                // 44

    // epilogue: C layout col=lane&15, row=(lane>>4)*4+reg (raw, no dinv)
    #pragma unroll
    for (int mi = 0; mi < 2; ++mi) {
        #pragma unroll
        for (int reg = 0; reg < 4; ++reg) {
            int grow = rowBase + wm * 32 + mi * 16 + u * 4 + reg;
            if (grow < M) {
                #pragma unroll
                for (int ni = 0; ni < 4; ++ni) {
                    int gcol = wn * 64 + ni * 16 + r;
                    h[(size_t)grow * HID + gcol] = f2bf(acc[mi][ni][reg]);
                }
            }
        }
    }
}

// ---------------- self-loop insert + dinv (one thread per node) --------------
__global__ void self_dinv(int* __restrict__ cnt, int* __restrict__ csr_f,
                          float* __restrict__ dinv,
                          int* __restrict__ ovf_cnt, int2* __restrict__ ovf, int n) {
    int i = blockIdx.x * 256 + threadIdx.x;
    if (i >= n) return;
    int c = cnt[i];
    if (c < CAP) csr_f[i * CAP + c] = i;
    else { int op = atomicAdd(ovf_cnt, 1); ovf[op] = make_int2(i, i); }
    cnt[i] = c + 1;
    dinv[i] = rsqrtf((float)(c + 1));
}

// ---------------- Aggregation 1 + bias + relu + @W2 fused ----------------
__global__ __launch_bounds__(256) void agg1(const unsigned short* __restrict__ h,
                                            const int* __restrict__ cnt,
                                            const int* __restrict__ csr_f,
                                            const float* __restrict__ dinv,
                                            const float* __restrict__ b1,
                                            const float* __restrict__ W2,
                                            const int* __restrict__ ovf_cnt,
                                            const int2* __restrict__ ovf,
                                            float* __restrict__ h2s, int n) {
    __shared__ float W2s[HID * NCLS];
    for (int i = threadIdx.x; i < HID * NCLS; i += 256) W2s[i] = W2[i];
    __syncthreads();
    int wave = threadIdx.x >> 6, lane = threadIdx.x & 63;
    int v = blockIdx.x * 4 + wave;
    if (v >= n) return;
    const int fr = lane & 15, g = lane >> 4;
    int total = cnt[v];
    int inrow = min(total, CAP);
    const int base = v * CAP;
    float acc[8] = {};
    #pragma unroll 4
    for (int j = g; j < inrow; j += 4) {
        int s = csr_f[base + j];
        float ds = dinv[s];
        uint4 q = *(const uint4*)(h + (size_t)s * HID + fr * 8);
        unsigned int w[4] = {q.x, q.y, q.z, q.w};
        #pragma unroll
        for (int p = 0; p < 4; ++p) {
            acc[p * 2 + 0] += ds * u2f(w[p] << 16);          // low bf16
            acc[p * 2 + 1] += ds * u2f(w[p] & 0xffff0000u);  // high bf16
        }
    }
    if (__builtin_expect(total > CAP, 0) && g == 0) {
        int on = *ovf_cnt;
        for (int k = 0; k < on; ++k) {
            int2 pr = ovf[k];
            if (pr.x == v) {
                int s = pr.y;
                float ds = dinv[s];
                uint4 q = *(const uint4*)(h + (size_t)s * HID + fr * 8);
                unsigned int w[4] = {q.x, q.y, q.z, q.w};
                #pragma unroll
                for (int p = 0; p < 4; ++p) {
                    acc[p * 2 + 0] += ds * u2f(w[p] << 16);
                    acc[p * 2 + 1] += ds * u2f(w[p] & 0xffff0000u);
                }
            }
        }
    }
    #pragma unroll
    for (int e = 0; e < 8; ++e) {
        acc[e] += __shfl_xor(acc[e], 16, 64);
        acc[e] += __shfl_xor(acc[e], 32, 64);
    }
    float dv = dinv[v];
    float p[NCLS];
    #pragma unroll
    for (int c = 0; c < NCLS; ++c) p[c] = 0.f;
    #pragma unroll
    for (int e = 0; e < 8; ++e) {
        int f = fr * 8 + e;
        float val = fmaxf(dv * acc[e] + b1[f], 0.f);
        #pragma unroll
        for (int c = 0; c < NCLS; ++c) p[c] += val * W2s[f * NCLS + c];
    }
    #pragma unroll
    for (int off = 8; off >= 1; off >>= 1)
        #pragma unroll
        for (int c = 0; c < NCLS; ++c)
            p[c] += __shfl_xor(p[c], off, 64);
    if (lane == 0) {
        #pragma unroll
        for (int c = 0; c < NCLS; ++c) h2s[(size_t)v * 8 + c] = dv * p[c];  // pre-scaled
        h2s[(size_t)v * 8 + 7] = 0.f;
    }
}

// ---------------- Aggregation 2 + bias ----------------
__global__ __launch_bounds__(256) void agg2(const float* __restrict__ h2s,
                                            const int* __restrict__ cnt,
                                            const int* __restrict__ csr_f,
                                            const float* __restrict__ dinv,
                                            const float* __restrict__ b2,
                                            const int* __restrict__ ovf_cnt,
                                            const int2* __restrict__ ovf,
                                            float* __restrict__ out, int n) {
    int wave = threadIdx.x >> 6, lane = threadIdx.x & 63;
    int half = lane >> 5;
    int c = lane & 7, g = (lane >> 3) & 3;
    int v = blockIdx.x * 8 + wave * 2 + half;
    if (v >= n) return;
    int total = cnt[v];
    int inrow = min(total, CAP);
    const int base = v * CAP;
    float acc = 0.f;
    #pragma unroll 4
    for (int j = g; j < inrow; j += 4) {
        int s = csr_f[base + j];
        acc += h2s[(size_t)s * 8 + c];
    }
    if (__builtin_expect(total > CAP, 0) && g == 0) {
        int on = *ovf_cnt;
        for (int k = 0; k < on; ++k) {
            int2 pr = ovf[k];
            if (pr.x == v) acc += h2s[(size_t)pr.y * 8 + c];
        }
    }
    acc += __shfl_xor(acc, 8, 64);
    acc += __shfl_xor(acc, 16, 64);
    if (g == 0 && c < NCLS) out[(size_t)v * NCLS + c] = dinv[v] * acc + b2[c];
}

extern "C" void kernel_launch(void* const* d_in, const int* in_sizes, int n_in,
                              void* d_out, int out_size, void* d_ws, size_t ws_size,
                              hipStream_t stream) {
    const float* x  = (const float*)d_in[0];
    const int*   ei = (const int*)d_in[1];    // int64 in reference but JAX x64-off => int32
    const float* W1 = (const float*)d_in[2];
    const float* b1 = (const float*)d_in[3];
    const float* W2 = (const float*)d_in[4];
    const float* b2 = (const float*)d_in[5];
    float* out = (float*)d_out;

    const int N = NNODES;
    const int E = in_sizes[1] / 2;
    const int* src = ei;
    const int* dst = ei + E;
    const int GB = (N + BM - 1) / BM;         // gemm blocks (391)
    const int FB = (E + 4095) / 4096;         // fill blocks (512t x 8 edges)

    char* ws = (char*)d_ws;
    size_t off = 0;
    auto alloc = [&](size_t bytes) {
        void* p = ws + off;
        off += (bytes + 255) & ~(size_t)255;
        return p;
    };
    int*   cnt     = (int*)alloc((size_t)N * 4);
    int*   ovf_cnt = (int*)alloc(4);
    float* dinv    = (float*)alloc((size_t)N * 4);
    int*   csr_f   = (int*)alloc((size_t)N * CAP * 4);
    int2*  ovf     = (int2*)alloc((size_t)4096 * 8);
    unsigned short* W1s = (unsigned short*)alloc((size_t)KT1 * 512 * 8 * 2);
    unsigned short* h   = (unsigned short*)alloc((size_t)N * HID * 2);
    float* h2s     = (float*)alloc((size_t)N * 8 * 4);

    // zero cnt + ovf_cnt (contiguous allocations)
    (void)hipMemsetAsync(cnt, 0, ((char*)ovf_cnt - (char*)cnt) + 256, stream);
    prep_w1<<<(KT1 * 512 + 511) / 512, 512, 0, stream>>>(W1, W1s);
    gemm_fill<<<GB + FB, 512, 0, stream>>>(x, W1s, h, N, src, dst, E,
                                           cnt, csr_f, ovf_cnt, ovf, GB);
    self_dinv<<<(N + 255) / 256, 256, 0, stream>>>(cnt, csr_f, dinv, ovf_cnt, ovf, N);
    agg1<<<(N + 3) / 4, 256, 0, stream>>>(h, cnt, csr_f, dinv, b1, W2, ovf_cnt, ovf, h2s, N);
    agg2<<<(N + 7) / 8, 256, 0, stream>>>(h2s, cnt, csr_f, dinv, b2, ovf_cnt, ovf, out, N);
}

// Round 21
// 238.682 us; speedup vs baseline: 1.1694x; 1.0254x over previous
//
#include <hip/hip_runtime.h>
#include <hip/hip_bf16.h>

typedef __attribute__((ext_vector_type(8))) short short8_t;
typedef __attribute__((ext_vector_type(4))) float f32x4;
typedef float f32x4u __attribute__((ext_vector_type(4), aligned(4)));  // 4B-aligned vector load

#define NNODES 50000
#define FIN 1433
#define HID 128
#define NCLS 7
#define KT1 45          // ceil(1433/32)
#define BK 32
#define BM 64
#define CAP 96          // fixed CSR slots/node; Poisson(32) => P(deg>96) ~ 0; exact via ovf
#define GSTR 520        // A LDS g-stride in ushorts (64*8 + 8 pad; <=2-way conflicts = free)

static __device__ __forceinline__ unsigned short f2bf(float f) {
    union { float f; unsigned int u; } v; v.f = f;
    unsigned int u = v.u;
    u += 0x7FFFu + ((u >> 16) & 1u);   // round-to-nearest-even
    return (unsigned short)(u >> 16);
}
static __device__ __forceinline__ float u2f(unsigned int u) {
    union { unsigned int u; float f; } v; v.u = u; return v.f;
}

// ---------------- W1 pack: W1[FIN][HID] f32 -> W1s[KT1][512 segs][8 bf16]
__global__ void prep_w1(const float* __restrict__ W1, unsigned short* __restrict__ W1s) {
    int tid = blockIdx.x * 512 + threadIdx.x;
    if (tid >= KT1 * 512) return;
    int kt = tid >> 9, seg = tid & 511;
    int c = seg & 127, g = seg >> 7;
    int kb = kt * BK + g * 8;
    unsigned int w[4];
    #pragma unroll
    for (int p = 0; p < 4; ++p) {
        int k0 = kb + p * 2, k1 = kb + p * 2 + 1;
        unsigned short lo = (k0 < FIN) ? f2bf(W1[(size_t)k0 * HID + c]) : (unsigned short)0;
        unsigned short hi = (k1 < FIN) ? f2bf(W1[(size_t)k1 * HID + c]) : (unsigned short)0;
        w[p] = (unsigned int)lo | ((unsigned int)hi << 16);
    }
    uint4* dstp = (uint4*)(W1s + (size_t)tid * 8);
    uint4 val; val.x = w[0]; val.y = w[1]; val.z = w[2]; val.w = w[3];
    *dstp = val;
}

// ---------------- FAT kernel: gemm blocks [0,gb) || FILL blocks [gb, grid) ---
// GEMM: BM=64, BK=32, 512t (8 waves = 4 row-groups x 2 col-groups, 1x4 tiles
// per wave). ~33KB LDS -> 4 blocks/CU; grid 782+196=978 <= 1024 slots ->
// single shot over ALL 256 CUs (R17 had 93 CUs idle). R17 pipeline otherwise.
// FILL: fixed-stride CSR scatter, 512t x 16 edges.
__global__ __launch_bounds__(512) void gemm_fill(const float* __restrict__ x,
                                                 const unsigned short* __restrict__ W1s,
                                                 unsigned short* __restrict__ h, int M,
                                                 const int* __restrict__ src,
                                                 const int* __restrict__ dst, int E,
                                                 int* __restrict__ cnt,
                                                 int* __restrict__ csr_f,
                                                 int* __restrict__ ovf_cnt,
                                                 int2* __restrict__ ovf, int gb) {
    __shared__ unsigned short As[2][2080];   // [g^(row&3)][row 64][8], GSTR=520
    __shared__ unsigned short Bs[3][4096];   // [g 4][c 128][8] linear (gload_lds)

    if (blockIdx.x >= gb) {
        // ---- fill blocks: 512 threads x 16 edges (two 8-chunks) ----
        int bid = blockIdx.x - gb;
        #pragma unroll
        for (int half = 0; half < 2; ++half) {
            int i = (bid * 1024 + half * 512 + (int)threadIdx.x) * 8;
            if (i + 7 < E) {
                int4 d0 = *(const int4*)(dst + i);
                int4 d1 = *(const int4*)(dst + i + 4);
                int4 s0 = *(const int4*)(src + i);
                int4 s1 = *(const int4*)(src + i + 4);
                int dd[8] = {d0.x, d0.y, d0.z, d0.w, d1.x, d1.y, d1.z, d1.w};
                int ss[8] = {s0.x, s0.y, s0.z, s0.w, s1.x, s1.y, s1.z, s1.w};
                #pragma unroll
                for (int e = 0; e < 8; ++e) {
                    int pos = atomicAdd(&cnt[dd[e]], 1);
                    if (pos < CAP) csr_f[dd[e] * CAP + pos] = ss[e];
                    else { int op = atomicAdd(ovf_cnt, 1); ovf[op] = make_int2(dd[e], ss[e]); }
                }
            } else if (i < E) {
                for (int e = i; e < E; ++e) {
                    int d = dst[e], s = src[e];
                    int pos = atomicAdd(&cnt[d], 1);
                    if (pos < CAP) csr_f[d * CAP + pos] = s;
                    else { int op = atomicAdd(ovf_cnt, 1); ovf[op] = make_int2(d, s); }
                }
            }
        }
        return;
    }

    // ---- gemm blocks ----
    const int t = threadIdx.x;
    const int wave = t >> 6, lane = t & 63;
    const int wm = wave >> 1, wn = wave & 1;      // wm 0..3 row-group, wn 0..1 col-group
    const int r = lane & 15, u = lane >> 4;       // u in 0..3 = K-octet & row-quad
    const int rowBase = blockIdx.x * BM;
    f32x4 acc[4] = {};

    float4 areg;   // 1 f32x4 per thread per tile (64 rows x 8 quads = 512)

    auto issueA = [&](int kt) {
        int k0 = kt * BK;
        int row = t >> 3, kq = t & 7;
        int gr = min(rowBase + row, M - 1);       // clamp; OOB rows unstored
        int gk = k0 + kq * 4;                     // in-bounds for kt <= 43
        f32x4u v = *(const f32x4u*)(x + (size_t)gr * FIN + gk);
        areg.x = v.x; areg.y = v.y; areg.z = v.z; areg.w = v.w;
    };
    auto issueA_tail = [&]() {                    // kt=44: k 1408..1439, guard FIN
        int row = t >> 3, kq = t & 7;
        int gr = min(rowBase + row, M - 1);
        int gk = 1408 + kq * 4;
        const float* p = x + (size_t)gr * FIN;
        areg.x = (gk + 0 < FIN) ? p[gk + 0] : 0.f;
        areg.y = (gk + 1 < FIN) ? p[gk + 1] : 0.f;
        areg.z = (gk + 2 < FIN) ? p[gk + 2] : 0.f;
        areg.w = (gk + 3 < FIN) ? p[gk + 3] : 0.f;
    };
    auto issueB = [&](int kt, int buf) {
        const unsigned short* gp = W1s + ((size_t)kt * 512 + t) * 8;
        unsigned short* lp = &Bs[buf][(wave * 64) * 8];
        __builtin_amdgcn_global_load_lds(
            (const __attribute__((address_space(1))) unsigned int*)gp,
            (__attribute__((address_space(3))) unsigned int*)lp, 16, 0, 0);
    };
    auto writeA = [&](int buf) {
        int row = t >> 3, kq = t & 7;
        __hip_bfloat162 lo2 = __float22bfloat162_rn(make_float2(areg.x, areg.y));
        __hip_bfloat162 hi2 = __float22bfloat162_rn(make_float2(areg.z, areg.w));
        unsigned int ulo, uhi;
        __builtin_memcpy(&ulo, &lo2, 4);
        __builtin_memcpy(&uhi, &hi2, 4);
        unsigned long long pk = ((unsigned long long)uhi << 32) | (unsigned long long)ulo;
        int g = kq >> 1, half = kq & 1;
        int us = ((g ^ (row & 3)) * GSTR) + row * 8 + half * 4;
        *(unsigned long long*)(&As[buf][us]) = pk;
    };
    auto compute = [&](int kt) {
        const int abuf = kt & 1, bbuf = kt % 3;
        short8_t af, bfr[4];
        {
            int row = wm * 16 + r;
            int us = ((u ^ (row & 3)) * GSTR) + row * 8;
            af = *(const short8_t*)(&As[abuf][us]);
        }
        #pragma unroll
        for (int ni = 0; ni < 4; ++ni) {
            int c = wn * 64 + ni * 16 + r;
            bfr[ni] = *(const short8_t*)(&Bs[bbuf][u * 1024 + c * 8]);
        }
        #pragma unroll
        for (int ni = 0; ni < 4; ++ni)
            acc[ni] = __builtin_amdgcn_mfma_f32_16x16x32_bf16(af, bfr[ni], acc[ni], 0, 0, 0);
    };

    // prologue: tile 0 staged; tile 1 in flight
    issueA(0); issueB(0, 0);
    writeA(0);                       // implicit wait on A(0)
    issueA(1); issueB(1, 1);
    __syncthreads();                 // drains B(0); A(1)/B(1) complete too

    // main loop: kt = 0..41 (issues up to tile 43; tiles 0..43 all k-in-bounds)
    for (int kt = 0; kt < KT1 - 3; ++kt) {
        compute(kt);
        writeA((kt + 1) & 1);        // A(t+1) loads landed by prev barrier
        issueA(kt + 2);
        issueB(kt + 2, (kt + 2) % 3);
        __syncthreads();             // one barrier/iter; 4-block TLP hides drain
    }
    // kt = 42
    {
        compute(KT1 - 3);            // 42
        writeA((KT1 - 2) & 1);       // A(43) -> As[1]
        __syncthreads();
    }
    // stage guarded tail tile 44
    issueA_tail();
    issueB(KT1 - 1, (KT1 - 1) % 3);  // B(44) -> Bs[2]
    writeA((KT1 - 1) & 1);           // A(44) -> As[0]
    __syncthreads();
    compute(KT1 - 2);                // 43
    compute(KT1 - 1);                // 44

    // epilogue: C layout col=lane&15, row=(lane>>4)*4+reg (raw, no dinv)
    #pragma unroll
    for (int reg = 0; reg < 4; ++reg) {
        int grow = rowBase + wm * 16 + u * 4 + reg;
        if (grow < M) {
            #pragma unroll
            for (int ni = 0; ni < 4; ++ni) {
                int gcol = wn * 64 + ni * 16 + r;
                h[(size_t)grow * HID + gcol] = f2bf(acc[ni][reg]);
            }
        }
    }
}

// ---------------- self-loop insert + dinv (one thread per node) --------------
__global__ void self_dinv(int* __restrict__ cnt, int* __restrict__ csr_f,
                          float* __restrict__ dinv,
                          int* __restrict__ ovf_cnt, int2* __restrict__ ovf, int n) {
    int i = blockIdx.x * 256 + threadIdx.x;
    if (i >= n) return;
    int c = cnt[i];
    if (c < CAP) csr_f[i * CAP + c] = i;
    else { int op = atomicAdd(ovf_cnt, 1); ovf[op] = make_int2(i, i); }
    cnt[i] = c + 1;
    dinv[i] = rsqrtf((float)(c + 1));
}

// ---------------- Aggregation 1 + bias + relu + @W2 fused ----------------
__global__ __launch_bounds__(256) void agg1(const unsigned short* __restrict__ h,
                                            const int* __restrict__ cnt,
                                            const int* __restrict__ csr_f,
                                            const float* __restrict__ dinv,
                                            const float* __restrict__ b1,
                                            const float* __restrict__ W2,
                                            const int* __restrict__ ovf_cnt,
                                            const int2* __restrict__ ovf,
                                            float* __restrict__ h2s, int n) {
    __shared__ float W2s[HID * NCLS];
    for (int i = threadIdx.x; i < HID * NCLS; i += 256) W2s[i] = W2[i];
    __syncthreads();
    int wave = threadIdx.x >> 6, lane = threadIdx.x & 63;
    int v = blockIdx.x * 4 + wave;
    if (v >= n) return;
    const int fr = lane & 15, g = lane >> 4;
    int total = cnt[v];
    int inrow = min(total, CAP);
    const int base = v * CAP;
    float acc[8] = {};
    #pragma unroll 4
    for (int j = g; j < inrow; j += 4) {
        int s = csr_f[base + j];
        float ds = dinv[s];
        uint4 q = *(const uint4*)(h + (size_t)s * HID + fr * 8);
        unsigned int w[4] = {q.x, q.y, q.z, q.w};
        #pragma unroll
        for (int p = 0; p < 4; ++p) {
            acc[p * 2 + 0] += ds * u2f(w[p] << 16);          // low bf16
            acc[p * 2 + 1] += ds * u2f(w[p] & 0xffff0000u);  // high bf16
        }
    }
    if (__builtin_expect(total > CAP, 0) && g == 0) {
        int on = *ovf_cnt;
        for (int k = 0; k < on; ++k) {
            int2 pr = ovf[k];
            if (pr.x == v) {
                int s = pr.y;
                float ds = dinv[s];
                uint4 q = *(const uint4*)(h + (size_t)s * HID + fr * 8);
                unsigned int w[4] = {q.x, q.y, q.z, q.w};
                #pragma unroll
                for (int p = 0; p < 4; ++p) {
                    acc[p * 2 + 0] += ds * u2f(w[p] << 16);
                    acc[p * 2 + 1] += ds * u2f(w[p] & 0xffff0000u);
                }
            }
        }
    }
    #pragma unroll
    for (int e = 0; e < 8; ++e) {
        acc[e] += __shfl_xor(acc[e], 16, 64);
        acc[e] += __shfl_xor(acc[e], 32, 64);
    }
    float dv = dinv[v];
    float p[NCLS];
    #pragma unroll
    for (int c = 0; c < NCLS; ++c) p[c] = 0.f;
    #pragma unroll
    for (int e = 0; e < 8; ++e) {
        int f = fr * 8 + e;
        float val = fmaxf(dv * acc[e] + b1[f], 0.f);
        #pragma unroll
        for (int c = 0; c < NCLS; ++c) p[c] += val * W2s[f * NCLS + c];
    }
    #pragma unroll
    for (int off = 8; off >= 1; off >>= 1)
        #pragma unroll
        for (int c = 0; c < NCLS; ++c)
            p[c] += __shfl_xor(p[c], off, 64);
    if (lane == 0) {
        #pragma unroll
        for (int c = 0; c < NCLS; ++c) h2s[(size_t)v * 8 + c] = dv * p[c];  // pre-scaled
        h2s[(size_t)v * 8 + 7] = 0.f;
    }
}

// ---------------- Aggregation 2 + bias ----------------
__global__ __launch_bounds__(256) void agg2(const float* __restrict__ h2s,
                                            const int* __restrict__ cnt,
                                            const int* __restrict__ csr_f,
                                            const float* __restrict__ dinv,
                                            const float* __restrict__ b2,
                                            const int* __restrict__ ovf_cnt,
                                            const int2* __restrict__ ovf,
                                            float* __restrict__ out, int n) {
    int wave = threadIdx.x >> 6, lane = threadIdx.x & 63;
    int half = lane >> 5;
    int c = lane & 7, g = (lane >> 3) & 3;
    int v = blockIdx.x * 8 + wave * 2 + half;
    if (v >= n) return;
    int total = cnt[v];
    int inrow = min(total, CAP);
    const int base = v * CAP;
    float acc = 0.f;
    #pragma unroll 4
    for (int j = g; j < inrow; j += 4) {
        int s = csr_f[base + j];
        acc += h2s[(size_t)s * 8 + c];
    }
    if (__builtin_expect(total > CAP, 0) && g == 0) {
        int on = *ovf_cnt;
        for (int k = 0; k < on; ++k) {
            int2 pr = ovf[k];
            if (pr.x == v) acc += h2s[(size_t)pr.y * 8 + c];
        }
    }
    acc += __shfl_xor(acc, 8, 64);
    acc += __shfl_xor(acc, 16, 64);
    if (g == 0 && c < NCLS) out[(size_t)v * NCLS + c] = dinv[v] * acc + b2[c];
}

extern "C" void kernel_launch(void* const* d_in, const int* in_sizes, int n_in,
                              void* d_out, int out_size, void* d_ws, size_t ws_size,
                              hipStream_t stream) {
    const float* x  = (const float*)d_in[0];
    const int*   ei = (const int*)d_in[1];    // int64 in reference but JAX x64-off => int32
    const float* W1 = (const float*)d_in[2];
    const float* b1 = (const float*)d_in[3];
    const float* W2 = (const float*)d_in[4];
    const float* b2 = (const float*)d_in[5];
    float* out = (float*)d_out;

    const int N = NNODES;
    const int E = in_sizes[1] / 2;
    const int* src = ei;
    const int* dst = ei + E;
    const int GB = (N + BM - 1) / BM;         // gemm blocks (782)
    const int FB = (E + 8191) / 8192;         // fill blocks (512t x 16 edges)

    char* ws = (char*)d_ws;
    size_t off = 0;
    auto alloc = [&](size_t bytes) {
        void* p = ws + off;
        off += (bytes + 255) & ~(size_t)255;
        return p;
    };
    int*   cnt     = (int*)alloc((size_t)N * 4);
    int*   ovf_cnt = (int*)alloc(4);
    float* dinv    = (float*)alloc((size_t)N * 4);
    int*   csr_f   = (int*)alloc((size_t)N * CAP * 4);
    int2*  ovf     = (int2*)alloc((size_t)4096 * 8);
    unsigned short* W1s = (unsigned short*)alloc((size_t)KT1 * 512 * 8 * 2);
    unsigned short* h   = (unsigned short*)alloc((size_t)N * HID * 2);
    float* h2s     = (float*)alloc((size_t)N * 8 * 4);

    // zero cnt + ovf_cnt (contiguous allocations)
    (void)hipMemsetAsync(cnt, 0, ((char*)ovf_cnt - (char*)cnt) + 256, stream);
    prep_w1<<<(KT1 * 512 + 511) / 512, 512, 0, stream>>>(W1, W1s);
    gemm_fill<<<GB + FB, 512, 0, stream>>>(x, W1s, h, N, src, dst, E,
                                           cnt, csr_f, ovf_cnt, ovf, GB);
    self_dinv<<<(N + 255) / 256, 256, 0, stream>>>(cnt, csr_f, dinv, ovf_cnt, ovf, N);
    agg1<<<(N + 3) / 4, 256, 0, stream>>>(h, cnt, csr_f, dinv, b1, W2, ovf_cnt, ovf, h2s, N);
    agg2<<<(N + 7) / 8, 256, 0, stream>>>(h2s, cnt, csr_f, dinv, b2, ovf_cnt, ovf, out, N);
}

// Round 22
// 235.991 us; speedup vs baseline: 1.1827x; 1.0114x over previous
//
#include <hip/hip_runtime.h>
#include <hip/hip_bf16.h>

typedef __attribute__((ext_vector_type(8))) short short8_t;
typedef __attribute__((ext_vector_type(4))) float f32x4;
typedef float f32x4u __attribute__((ext_vector_type(4), aligned(4)));  // 4B-aligned vector load

#define NNODES 50000
#define FIN 1433
#define HID 128
#define NCLS 7
#define KT1 45          // ceil(1433/32)
#define BK 32
#define BM 64
#define CAP 96          // fixed CSR slots/node; Poisson(32) => P(deg>96) ~ 0; exact via ovf
#define GSTR 520        // A LDS g-stride in ushorts

static __device__ __forceinline__ unsigned short f2bf(float f) {
    union { float f; unsigned int u; } v; v.f = f;
    unsigned int u = v.u;
    u += 0x7FFFu + ((u >> 16) & 1u);   // round-to-nearest-even
    return (unsigned short)(u >> 16);
}
static __device__ __forceinline__ float u2f(unsigned int u) {
    union { unsigned int u; float f; } v; v.u = u; return v.f;
}

// ---------------- W1 pack: W1[FIN][HID] f32 -> W1s[KT1][512 segs][8 bf16]
__global__ void prep_w1(const float* __restrict__ W1, unsigned short* __restrict__ W1s) {
    int tid = blockIdx.x * 512 + threadIdx.x;
    if (tid >= KT1 * 512) return;
    int kt = tid >> 9, seg = tid & 511;
    int c = seg & 127, g = seg >> 7;
    int kb = kt * BK + g * 8;
    unsigned int w[4];
    #pragma unroll
    for (int p = 0; p < 4; ++p) {
        int k0 = kb + p * 2, k1 = kb + p * 2 + 1;
        unsigned short lo = (k0 < FIN) ? f2bf(W1[(size_t)k0 * HID + c]) : (unsigned short)0;
        unsigned short hi = (k1 < FIN) ? f2bf(W1[(size_t)k1 * HID + c]) : (unsigned short)0;
        w[p] = (unsigned int)lo | ((unsigned int)hi << 16);
    }
    uint4* dstp = (uint4*)(W1s + (size_t)tid * 8);
    uint4 val; val.x = w[0]; val.y = w[1]; val.z = w[2]; val.w = w[3];
    *dstp = val;
}

// ---------------- FAT kernel: gemm blocks [0,gb) || FILL blocks [gb, grid) ---
// R21 structure (machine-wide-BW-bound plateau). FILL: in-edges only, no self.
__global__ __launch_bounds__(512) void gemm_fill(const float* __restrict__ x,
                                                 const unsigned short* __restrict__ W1s,
                                                 unsigned short* __restrict__ h, int M,
                                                 const int* __restrict__ src,
                                                 const int* __restrict__ dst, int E,
                                                 int* __restrict__ cnt,
                                                 int* __restrict__ csr_f,
                                                 int* __restrict__ ovf_cnt,
                                                 int2* __restrict__ ovf, int gb) {
    __shared__ unsigned short As[2][2080];   // [g^(row&3)][row 64][8], GSTR=520
    __shared__ unsigned short Bs[3][4096];   // [g 4][c 128][8] linear (gload_lds)

    if (blockIdx.x >= gb) {
        // ---- fill blocks: 512 threads x 16 edges (two 8-chunks) ----
        int bid = blockIdx.x - gb;
        #pragma unroll
        for (int half = 0; half < 2; ++half) {
            int i = (bid * 1024 + half * 512 + (int)threadIdx.x) * 8;
            if (i + 7 < E) {
                int4 d0 = *(const int4*)(dst + i);
                int4 d1 = *(const int4*)(dst + i + 4);
                int4 s0 = *(const int4*)(src + i);
                int4 s1 = *(const int4*)(src + i + 4);
                int dd[8] = {d0.x, d0.y, d0.z, d0.w, d1.x, d1.y, d1.z, d1.w};
                int ss[8] = {s0.x, s0.y, s0.z, s0.w, s1.x, s1.y, s1.z, s1.w};
                #pragma unroll
                for (int e = 0; e < 8; ++e) {
                    int pos = atomicAdd(&cnt[dd[e]], 1);
                    if (pos < CAP) csr_f[dd[e] * CAP + pos] = ss[e];
                    else { int op = atomicAdd(ovf_cnt, 1); ovf[op] = make_int2(dd[e], ss[e]); }
                }
            } else if (i < E) {
                for (int e = i; e < E; ++e) {
                    int d = dst[e], s = src[e];
                    int pos = atomicAdd(&cnt[d], 1);
                    if (pos < CAP) csr_f[d * CAP + pos] = s;
                    else { int op = atomicAdd(ovf_cnt, 1); ovf[op] = make_int2(d, s); }
                }
            }
        }
        return;
    }

    // ---- gemm blocks ----
    const int t = threadIdx.x;
    const int wave = t >> 6, lane = t & 63;
    const int wm = wave >> 1, wn = wave & 1;
    const int r = lane & 15, u = lane >> 4;
    const int rowBase = blockIdx.x * BM;
    f32x4 acc[4] = {};

    float4 areg;

    auto issueA = [&](int kt) {
        int k0 = kt * BK;
        int row = t >> 3, kq = t & 7;
        int gr = min(rowBase + row, M - 1);
        int gk = k0 + kq * 4;
        f32x4u v = *(const f32x4u*)(x + (size_t)gr * FIN + gk);
        areg.x = v.x; areg.y = v.y; areg.z = v.z; areg.w = v.w;
    };
    auto issueA_tail = [&]() {
        int row = t >> 3, kq = t & 7;
        int gr = min(rowBase + row, M - 1);
        int gk = 1408 + kq * 4;
        const float* p = x + (size_t)gr * FIN;
        areg.x = (gk + 0 < FIN) ? p[gk + 0] : 0.f;
        areg.y = (gk + 1 < FIN) ? p[gk + 1] : 0.f;
        areg.z = (gk + 2 < FIN) ? p[gk + 2] : 0.f;
        areg.w = (gk + 3 < FIN) ? p[gk + 3] : 0.f;
    };
    auto issueB = [&](int kt, int buf) {
        const unsigned short* gp = W1s + ((size_t)kt * 512 + t) * 8;
        unsigned short* lp = &Bs[buf][(wave * 64) * 8];
        __builtin_amdgcn_global_load_lds(
            (const __attribute__((address_space(1))) unsigned int*)gp,
            (__attribute__((address_space(3))) unsigned int*)lp, 16, 0, 0);
    };
    auto writeA = [&](int buf) {
        int row = t >> 3, kq = t & 7;
        __hip_bfloat162 lo2 = __float22bfloat162_rn(make_float2(areg.x, areg.y));
        __hip_bfloat162 hi2 = __float22bfloat162_rn(make_float2(areg.z, areg.w));
        unsigned int ulo, uhi;
        __builtin_memcpy(&ulo, &lo2, 4);
        __builtin_memcpy(&uhi, &hi2, 4);
        unsigned long long pk = ((unsigned long long)uhi << 32) | (unsigned long long)ulo;
        int g = kq >> 1, half = kq & 1;
        int us = ((g ^ (row & 3)) * GSTR) + row * 8 + half * 4;
        *(unsigned long long*)(&As[buf][us]) = pk;
    };
    auto compute = [&](int kt) {
        const int abuf = kt & 1, bbuf = kt % 3;
        short8_t af, bfr[4];
        {
            int row = wm * 16 + r;
            int us = ((u ^ (row & 3)) * GSTR) + row * 8;
            af = *(const short8_t*)(&As[abuf][us]);
        }
        #pragma unroll
        for (int ni = 0; ni < 4; ++ni) {
            int c = wn * 64 + ni * 16 + r;
            bfr[ni] = *(const short8_t*)(&Bs[bbuf][u * 1024 + c * 8]);
        }
        #pragma unroll
        for (int ni = 0; ni < 4; ++ni)
            acc[ni] = __builtin_amdgcn_mfma_f32_16x16x32_bf16(af, bfr[ni], acc[ni], 0, 0, 0);
    };

    issueA(0); issueB(0, 0);
    writeA(0);
    issueA(1); issueB(1, 1);
    __syncthreads();

    for (int kt = 0; kt < KT1 - 3; ++kt) {
        compute(kt);
        writeA((kt + 1) & 1);
        issueA(kt + 2);
        issueB(kt + 2, (kt + 2) % 3);
        __syncthreads();
    }
    {
        compute(KT1 - 3);
        writeA((KT1 - 2) & 1);
        __syncthreads();
    }
    issueA_tail();
    issueB(KT1 - 1, (KT1 - 1) % 3);
    writeA((KT1 - 1) & 1);
    __syncthreads();
    compute(KT1 - 2);
    compute(KT1 - 1);

    #pragma unroll
    for (int reg = 0; reg < 4; ++reg) {
        int grow = rowBase + wm * 16 + u * 4 + reg;
        if (grow < M) {
            #pragma unroll
            for (int ni = 0; ni < 4; ++ni) {
                int gcol = wn * 64 + ni * 16 + r;
                h[(size_t)grow * HID + gcol] = f2bf(acc[ni][reg]);
            }
        }
    }
}

// ---------------- Aggregation 1 + bias + relu + @W2 fused ----------------
// cnt = in-edge count (deg = cnt+1, dinv computed on the fly); self-loop
// contribution dv*h[v] added explicitly (csr holds only in-edges).
__global__ __launch_bounds__(256) void agg1(const unsigned short* __restrict__ h,
                                            const int* __restrict__ cnt,
                                            const int* __restrict__ csr_f,
                                            const float* __restrict__ b1,
                                            const float* __restrict__ W2,
                                            const int* __restrict__ ovf_cnt,
                                            const int2* __restrict__ ovf,
                                            float* __restrict__ h2s, int n) {
    __shared__ float W2s[HID * NCLS];
    for (int i = threadIdx.x; i < HID * NCLS; i += 256) W2s[i] = W2[i];
    __syncthreads();
    int wave = threadIdx.x >> 6, lane = threadIdx.x & 63;
    int v = blockIdx.x * 4 + wave;
    if (v >= n) return;
    const int fr = lane & 15, g = lane >> 4;
    int total = cnt[v];                 // in-edges only
    float dv = rsqrtf((float)(total + 1));
    int inrow = min(total, CAP);
    const int base = v * CAP;
    float acc[8] = {};
    // self-loop (group 0 only; combined via shfl reduce below)
    if (g == 0) {
        uint4 q = *(const uint4*)(h + (size_t)v * HID + fr * 8);
        unsigned int w[4] = {q.x, q.y, q.z, q.w};
        #pragma unroll
        for (int p = 0; p < 4; ++p) {
            acc[p * 2 + 0] += dv * u2f(w[p] << 16);
            acc[p * 2 + 1] += dv * u2f(w[p] & 0xffff0000u);
        }
    }
    #pragma unroll 4
    for (int j = g; j < inrow; j += 4) {
        int s = csr_f[base + j];
        float ds = rsqrtf((float)(cnt[s] + 1));
        uint4 q = *(const uint4*)(h + (size_t)s * HID + fr * 8);
        unsigned int w[4] = {q.x, q.y, q.z, q.w};
        #pragma unroll
        for (int p = 0; p < 4; ++p) {
            acc[p * 2 + 0] += ds * u2f(w[p] << 16);          // low bf16
            acc[p * 2 + 1] += ds * u2f(w[p] & 0xffff0000u);  // high bf16
        }
    }
    if (__builtin_expect(total > CAP, 0) && g == 0) {
        int on = *ovf_cnt;
        for (int k = 0; k < on; ++k) {
            int2 pr = ovf[k];
            if (pr.x == v) {
                int s = pr.y;
                float ds = rsqrtf((float)(cnt[s] + 1));
                uint4 q = *(const uint4*)(h + (size_t)s * HID + fr * 8);
                unsigned int w[4] = {q.x, q.y, q.z, q.w};
                #pragma unroll
                for (int p = 0; p < 4; ++p) {
                    acc[p * 2 + 0] += ds * u2f(w[p] << 16);
                    acc[p * 2 + 1] += ds * u2f(w[p] & 0xffff0000u);
                }
            }
        }
    }
    #pragma unroll
    for (int e = 0; e < 8; ++e) {
        acc[e] += __shfl_xor(acc[e], 16, 64);
        acc[e] += __shfl_xor(acc[e], 32, 64);
    }
    float p[NCLS];
    #pragma unroll
    for (int c = 0; c < NCLS; ++c) p[c] = 0.f;
    #pragma unroll
    for (int e = 0; e < 8; ++e) {
        int f = fr * 8 + e;
        float val = fmaxf(dv * acc[e] + b1[f], 0.f);
        #pragma unroll
        for (int c = 0; c < NCLS; ++c) p[c] += val * W2s[f * NCLS + c];
    }
    #pragma unroll
    for (int off = 8; off >= 1; off >>= 1)
        #pragma unroll
        for (int c = 0; c < NCLS; ++c)
            p[c] += __shfl_xor(p[c], off, 64);
    if (lane == 0) {
        #pragma unroll
        for (int c = 0; c < NCLS; ++c) h2s[(size_t)v * 8 + c] = dv * p[c];  // pre-scaled
        h2s[(size_t)v * 8 + 7] = 0.f;
    }
}

// ---------------- Aggregation 2 + bias ----------------
// h2s pre-scaled by dinv[src]; self term = h2s[v] itself.
__global__ __launch_bounds__(256) void agg2(const float* __restrict__ h2s,
                                            const int* __restrict__ cnt,
                                            const int* __restrict__ csr_f,
                                            const float* __restrict__ b2,
                                            const int* __restrict__ ovf_cnt,
                                            const int2* __restrict__ ovf,
                                            float* __restrict__ out, int n) {
    int wave = threadIdx.x >> 6, lane = threadIdx.x & 63;
    int half = lane >> 5;
    int c = lane & 7, g = (lane >> 3) & 3;
    int v = blockIdx.x * 8 + wave * 2 + half;
    if (v >= n) return;
    int total = cnt[v];
    float dv = rsqrtf((float)(total + 1));
    int inrow = min(total, CAP);
    const int base = v * CAP;
    float acc = (g == 0) ? h2s[(size_t)v * 8 + c] : 0.f;   // self loop
    #pragma unroll 4
    for (int j = g; j < inrow; j += 4) {
        int s = csr_f[base + j];
        acc += h2s[(size_t)s * 8 + c];
    }
    if (__builtin_expect(total > CAP, 0) && g == 0) {
        int on = *ovf_cnt;
        for (int k = 0; k < on; ++k) {
            int2 pr = ovf[k];
            if (pr.x == v) acc += h2s[(size_t)pr.y * 8 + c];
        }
    }
    acc += __shfl_xor(acc, 8, 64);
    acc += __shfl_xor(acc, 16, 64);
    if (g == 0 && c < NCLS) out[(size_t)v * NCLS + c] = dv * acc + b2[c];
}

extern "C" void kernel_launch(void* const* d_in, const int* in_sizes, int n_in,
                              void* d_out, int out_size, void* d_ws, size_t ws_size,
                              hipStream_t stream) {
    const float* x  = (const float*)d_in[0];
    const int*   ei = (const int*)d_in[1];    // int64 in reference but JAX x64-off => int32
    const float* W1 = (const float*)d_in[2];
    const float* b1 = (const float*)d_in[3];
    const float* W2 = (const float*)d_in[4];
    const float* b2 = (const float*)d_in[5];
    float* out = (float*)d_out;

    const int N = NNODES;
    const int E = in_sizes[1] / 2;
    const int* src = ei;
    const int* dst = ei + E;
    const int GB = (N + BM - 1) / BM;         // gemm blocks (782)
    const int FB = (E + 8191) / 8192;         // fill blocks (512t x 16 edges)

    char* ws = (char*)d_ws;
    size_t off = 0;
    auto alloc = [&](size_t bytes) {
        void* p = ws + off;
        off += (bytes + 255) & ~(size_t)255;
        return p;
    };
    int*   cnt     = (int*)alloc((size_t)N * 4);
    int*   ovf_cnt = (int*)alloc(4);
    int*   csr_f   = (int*)alloc((size_t)N * CAP * 4);
    int2*  ovf     = (int2*)alloc((size_t)4096 * 8);
    unsigned short* W1s = (unsigned short*)alloc((size_t)KT1 * 512 * 8 * 2);
    unsigned short* h   = (unsigned short*)alloc((size_t)N * HID * 2);
    float* h2s     = (float*)alloc((size_t)N * 8 * 4);

    // zero cnt + ovf_cnt (contiguous allocations)
    (void)hipMemsetAsync(cnt, 0, ((char*)ovf_cnt - (char*)cnt) + 256, stream);
    prep_w1<<<(KT1 * 512 + 511) / 512, 512, 0, stream>>>(W1, W1s);
    gemm_fill<<<GB + FB, 512, 0, stream>>>(x, W1s, h, N, src, dst, E,
                                           cnt, csr_f, ovf_cnt, ovf, GB);
    agg1<<<(N + 3) / 4, 256, 0, stream>>>(h, cnt, csr_f, b1, W2, ovf_cnt, ovf, h2s, N);
    agg2<<<(N + 7) / 8, 256, 0, stream>>>(h2s, cnt, csr_f, b2, ovf_cnt, ovf, out, N);
}

// Round 23
// 234.281 us; speedup vs baseline: 1.1914x; 1.0073x over previous
//
#include <hip/hip_runtime.h>
#include <hip/hip_bf16.h>

typedef __attribute__((ext_vector_type(8))) short short8_t;
typedef __attribute__((ext_vector_type(4))) float f32x4;
typedef float f32x4u __attribute__((ext_vector_type(4), aligned(4)));  // 4B-aligned vector load

#define NNODES 50000
#define FIN 1433
#define HID 128
#define NCLS 7
#define KT1 45          // ceil(1433/32)
#define BK 32
#define BM 64
#define CAP 96          // fixed CSR slots/node (uint16 entries); exact via ovf
#define GSTR 520        // A LDS g-stride in ushorts

static __device__ __forceinline__ unsigned short f2bf(float f) {
    union { float f; unsigned int u; } v; v.f = f;
    unsigned int u = v.u;
    u += 0x7FFFu + ((u >> 16) & 1u);   // round-to-nearest-even
    return (unsigned short)(u >> 16);
}
static __device__ __forceinline__ float u2f(unsigned int u) {
    union { unsigned int u; float f; } v; v.u = u; return v.f;
}

// ---------------- W1 pack: W1[FIN][HID] f32 -> W1s[KT1][512 segs][8 bf16]
__global__ void prep_w1(const float* __restrict__ W1, unsigned short* __restrict__ W1s) {
    int tid = blockIdx.x * 512 + threadIdx.x;
    if (tid >= KT1 * 512) return;
    int kt = tid >> 9, seg = tid & 511;
    int c = seg & 127, g = seg >> 7;
    int kb = kt * BK + g * 8;
    unsigned int w[4];
    #pragma unroll
    for (int p = 0; p < 4; ++p) {
        int k0 = kb + p * 2, k1 = kb + p * 2 + 1;
        unsigned short lo = (k0 < FIN) ? f2bf(W1[(size_t)k0 * HID + c]) : (unsigned short)0;
        unsigned short hi = (k1 < FIN) ? f2bf(W1[(size_t)k1 * HID + c]) : (unsigned short)0;
        w[p] = (unsigned int)lo | ((unsigned int)hi << 16);
    }
    uint4* dstp = (uint4*)(W1s + (size_t)tid * 8);
    uint4 val; val.x = w[0]; val.y = w[1]; val.z = w[2]; val.w = w[3];
    *dstp = val;
}

// ---------------- FAT kernel: gemm blocks [0,gb) || FILL blocks [gb, grid) ---
// R21 gemm structure. FILL: fixed-stride CSR scatter with UINT16 entries
// (node ids < 65536) -> ~half the write-allocate line traffic vs int32.
__global__ __launch_bounds__(512) void gemm_fill(const float* __restrict__ x,
                                                 const unsigned short* __restrict__ W1s,
                                                 unsigned short* __restrict__ h, int M,
                                                 const int* __restrict__ src,
                                                 const int* __restrict__ dst, int E,
                                                 int* __restrict__ cnt,
                                                 unsigned short* __restrict__ csr_f,
                                                 int* __restrict__ ovf_cnt,
                                                 int2* __restrict__ ovf, int gb) {
    __shared__ unsigned short As[2][2080];   // [g^(row&3)][row 64][8], GSTR=520
    __shared__ unsigned short Bs[3][4096];   // [g 4][c 128][8] linear (gload_lds)

    if (blockIdx.x >= gb) {
        // ---- fill blocks: 512 threads x 16 edges (two 8-chunks) ----
        int bid = blockIdx.x - gb;
        #pragma unroll
        for (int half = 0; half < 2; ++half) {
            int i = (bid * 1024 + half * 512 + (int)threadIdx.x) * 8;
            if (i + 7 < E) {
                int4 d0 = *(const int4*)(dst + i);
                int4 d1 = *(const int4*)(dst + i + 4);
                int4 s0 = *(const int4*)(src + i);
                int4 s1 = *(const int4*)(src + i + 4);
                int dd[8] = {d0.x, d0.y, d0.z, d0.w, d1.x, d1.y, d1.z, d1.w};
                int ss[8] = {s0.x, s0.y, s0.z, s0.w, s1.x, s1.y, s1.z, s1.w};
                #pragma unroll
                for (int e = 0; e < 8; ++e) {
                    int pos = atomicAdd(&cnt[dd[e]], 1);
                    if (pos < CAP) csr_f[dd[e] * CAP + pos] = (unsigned short)ss[e];
                    else { int op = atomicAdd(ovf_cnt, 1); ovf[op] = make_int2(dd[e], ss[e]); }
                }
            } else if (i < E) {
                for (int e = i; e < E; ++e) {
                    int d = dst[e], s = src[e];
                    int pos = atomicAdd(&cnt[d], 1);
                    if (pos < CAP) csr_f[d * CAP + pos] = (unsigned short)s;
                    else { int op = atomicAdd(ovf_cnt, 1); ovf[op] = make_int2(d, s); }
                }
            }
        }
        return;
    }

    // ---- gemm blocks ----
    const int t = threadIdx.x;
    const int wave = t >> 6, lane = t & 63;
    const int wm = wave >> 1, wn = wave & 1;
    const int r = lane & 15, u = lane >> 4;
    const int rowBase = blockIdx.x * BM;
    f32x4 acc[4] = {};

    float4 areg;

    auto issueA = [&](int kt) {
        int k0 = kt * BK;
        int row = t >> 3, kq = t & 7;
        int gr = min(rowBase + row, M - 1);
        int gk = k0 + kq * 4;
        f32x4u v = *(const f32x4u*)(x + (size_t)gr * FIN + gk);
        areg.x = v.x; areg.y = v.y; areg.z = v.z; areg.w = v.w;
    };
    auto issueA_tail = [&]() {
        int row = t >> 3, kq = t & 7;
        int gr = min(rowBase + row, M - 1);
        int gk = 1408 + kq * 4;
        const float* p = x + (size_t)gr * FIN;
        areg.x = (gk + 0 < FIN) ? p[gk + 0] : 0.f;
        areg.y = (gk + 1 < FIN) ? p[gk + 1] : 0.f;
        areg.z = (gk + 2 < FIN) ? p[gk + 2] : 0.f;
        areg.w = (gk + 3 < FIN) ? p[gk + 3] : 0.f;
    };
    auto issueB = [&](int kt, int buf) {
        const unsigned short* gp = W1s + ((size_t)kt * 512 + t) * 8;
        unsigned short* lp = &Bs[buf][(wave * 64) * 8];
        __builtin_amdgcn_global_load_lds(
            (const __attribute__((address_space(1))) unsigned int*)gp,
            (__attribute__((address_space(3))) unsigned int*)lp, 16, 0, 0);
    };
    auto writeA = [&](int buf) {
        int row = t >> 3, kq = t & 7;
        __hip_bfloat162 lo2 = __float22bfloat162_rn(make_float2(areg.x, areg.y));
        __hip_bfloat162 hi2 = __float22bfloat162_rn(make_float2(areg.z, areg.w));
        unsigned int ulo, uhi;
        __builtin_memcpy(&ulo, &lo2, 4);
        __builtin_memcpy(&uhi, &hi2, 4);
        unsigned long long pk = ((unsigned long long)uhi << 32) | (unsigned long long)ulo;
        int g = kq >> 1, half = kq & 1;
        int us = ((g ^ (row & 3)) * GSTR) + row * 8 + half * 4;
        *(unsigned long long*)(&As[buf][us]) = pk;
    };
    auto compute = [&](int kt) {
        const int abuf = kt & 1, bbuf = kt % 3;
        short8_t af, bfr[4];
        {
            int row = wm * 16 + r;
            int us = ((u ^ (row & 3)) * GSTR) + row * 8;
            af = *(const short8_t*)(&As[abuf][us]);
        }
        #pragma unroll
        for (int ni = 0; ni < 4; ++ni) {
            int c = wn * 64 + ni * 16 + r;
            bfr[ni] = *(const short8_t*)(&Bs[bbuf][u * 1024 + c * 8]);
        }
        #pragma unroll
        for (int ni = 0; ni < 4; ++ni)
            acc[ni] = __builtin_amdgcn_mfma_f32_16x16x32_bf16(af, bfr[ni], acc[ni], 0, 0, 0);
    };

    issueA(0); issueB(0, 0);
    writeA(0);
    issueA(1); issueB(1, 1);
    __syncthreads();

    for (int kt = 0; kt < KT1 - 3; ++kt) {
        compute(kt);
        writeA((kt + 1) & 1);
        issueA(kt + 2);
        issueB(kt + 2, (kt + 2) % 3);
        __syncthreads();
    }
    {
        compute(KT1 - 3);
        writeA((KT1 - 2) & 1);
        __syncthreads();
    }
    issueA_tail();
    issueB(KT1 - 1, (KT1 - 1) % 3);
    writeA((KT1 - 1) & 1);
    __syncthreads();
    compute(KT1 - 2);
    compute(KT1 - 1);

    #pragma unroll
    for (int reg = 0; reg < 4; ++reg) {
        int grow = rowBase + wm * 16 + u * 4 + reg;
        if (grow < M) {
            #pragma unroll
            for (int ni = 0; ni < 4; ++ni) {
                int gcol = wn * 64 + ni * 16 + r;
                h[(size_t)grow * HID + gcol] = f2bf(acc[ni][reg]);
            }
        }
    }
}

// ---------------- Aggregation 1 + bias + relu + @W2 fused ----------------
__global__ __launch_bounds__(256) void agg1(const unsigned short* __restrict__ h,
                                            const int* __restrict__ cnt,
                                            const unsigned short* __restrict__ csr_f,
                                            const float* __restrict__ b1,
                                            const float* __restrict__ W2,
                                            const int* __restrict__ ovf_cnt,
                                            const int2* __restrict__ ovf,
                                            float* __restrict__ h2s, int n) {
    __shared__ float W2s[HID * NCLS];
    for (int i = threadIdx.x; i < HID * NCLS; i += 256) W2s[i] = W2[i];
    __syncthreads();
    int wave = threadIdx.x >> 6, lane = threadIdx.x & 63;
    int v = blockIdx.x * 4 + wave;
    if (v >= n) return;
    const int fr = lane & 15, g = lane >> 4;
    int total = cnt[v];                 // in-edges only
    float dv = rsqrtf((float)(total + 1));
    int inrow = min(total, CAP);
    const int base = v * CAP;
    float acc[8] = {};
    if (g == 0) {                        // self loop
        uint4 q = *(const uint4*)(h + (size_t)v * HID + fr * 8);
        unsigned int w[4] = {q.x, q.y, q.z, q.w};
        #pragma unroll
        for (int p = 0; p < 4; ++p) {
            acc[p * 2 + 0] += dv * u2f(w[p] << 16);
            acc[p * 2 + 1] += dv * u2f(w[p] & 0xffff0000u);
        }
    }
    #pragma unroll 4
    for (int j = g; j < inrow; j += 4) {
        int s = csr_f[base + j];
        float ds = rsqrtf((float)(cnt[s] + 1));
        uint4 q = *(const uint4*)(h + (size_t)s * HID + fr * 8);
        unsigned int w[4] = {q.x, q.y, q.z, q.w};
        #pragma unroll
        for (int p = 0; p < 4; ++p) {
            acc[p * 2 + 0] += ds * u2f(w[p] << 16);          // low bf16
            acc[p * 2 + 1] += ds * u2f(w[p] & 0xffff0000u);  // high bf16
        }
    }
    if (__builtin_expect(total > CAP, 0) && g == 0) {
        int on = *ovf_cnt;
        for (int k = 0; k < on; ++k) {
            int2 pr = ovf[k];
            if (pr.x == v) {
                int s = pr.y;
                float ds = rsqrtf((float)(cnt[s] + 1));
                uint4 q = *(const uint4*)(h + (size_t)s * HID + fr * 8);
                unsigned int w[4] = {q.x, q.y, q.z, q.w};
                #pragma unroll
                for (int p = 0; p < 4; ++p) {
                    acc[p * 2 + 0] += ds * u2f(w[p] << 16);
                    acc[p * 2 + 1] += ds * u2f(w[p] & 0xffff0000u);
                }
            }
        }
    }
    #pragma unroll
    for (int e = 0; e < 8; ++e) {
        acc[e] += __shfl_xor(acc[e], 16, 64);
        acc[e] += __shfl_xor(acc[e], 32, 64);
    }
    float p[NCLS];
    #pragma unroll
    for (int c = 0; c < NCLS; ++c) p[c] = 0.f;
    #pragma unroll
    for (int e = 0; e < 8; ++e) {
        int f = fr * 8 + e;
        float val = fmaxf(dv * acc[e] + b1[f], 0.f);
        #pragma unroll
        for (int c = 0; c < NCLS; ++c) p[c] += val * W2s[f * NCLS + c];
    }
    #pragma unroll
    for (int off = 8; off >= 1; off >>= 1)
        #pragma unroll
        for (int c = 0; c < NCLS; ++c)
            p[c] += __shfl_xor(p[c], off, 64);
    if (lane == 0) {
        #pragma unroll
        for (int c = 0; c < NCLS; ++c) h2s[(size_t)v * 8 + c] = dv * p[c];  // pre-scaled
        h2s[(size_t)v * 8 + 7] = 0.f;
    }
}

// ---------------- Aggregation 2 + bias ----------------
__global__ __launch_bounds__(256) void agg2(const float* __restrict__ h2s,
                                            const int* __restrict__ cnt,
                                            const unsigned short* __restrict__ csr_f,
                                            const float* __restrict__ b2,
                                            const int* __restrict__ ovf_cnt,
                                            const int2* __restrict__ ovf,
                                            float* __restrict__ out, int n) {
    int wave = threadIdx.x >> 6, lane = threadIdx.x & 63;
    int half = lane >> 5;
    int c = lane & 7, g = (lane >> 3) & 3;
    int v = blockIdx.x * 8 + wave * 2 + half;
    if (v >= n) return;
    int total = cnt[v];
    float dv = rsqrtf((float)(total + 1));
    int inrow = min(total, CAP);
    const int base = v * CAP;
    float acc = (g == 0) ? h2s[(size_t)v * 8 + c] : 0.f;   // self loop
    #pragma unroll 4
    for (int j = g; j < inrow; j += 4) {
        int s = csr_f[base + j];
        acc += h2s[(size_t)s * 8 + c];
    }
    if (__builtin_expect(total > CAP, 0) && g == 0) {
        int on = *ovf_cnt;
        for (int k = 0; k < on; ++k) {
            int2 pr = ovf[k];
            if (pr.x == v) acc += h2s[(size_t)pr.y * 8 + c];
        }
    }
    acc += __shfl_xor(acc, 8, 64);
    acc += __shfl_xor(acc, 16, 64);
    if (g == 0 && c < NCLS) out[(size_t)v * NCLS + c] = dv * acc + b2[c];
}

extern "C" void kernel_launch(void* const* d_in, const int* in_sizes, int n_in,
                              void* d_out, int out_size, void* d_ws, size_t ws_size,
                              hipStream_t stream) {
    const float* x  = (const float*)d_in[0];
    const int*   ei = (const int*)d_in[1];    // int64 in reference but JAX x64-off => int32
    const float* W1 = (const float*)d_in[2];
    const float* b1 = (const float*)d_in[3];
    const float* W2 = (const float*)d_in[4];
    const float* b2 = (const float*)d_in[5];
    float* out = (float*)d_out;

    const int N = NNODES;
    const int E = in_sizes[1] / 2;
    const int* src = ei;
    const int* dst = ei + E;
    const int GB = (N + BM - 1) / BM;         // gemm blocks (782)
    const int FB = (E + 8191) / 8192;         // fill blocks (512t x 16 edges)

    char* ws = (char*)d_ws;
    size_t off = 0;
    auto alloc = [&](size_t bytes) {
        void* p = ws + off;
        off += (bytes + 255) & ~(size_t)255;
        return p;
    };
    int*   cnt     = (int*)alloc((size_t)N * 4);
    int*   ovf_cnt = (int*)alloc(4);
    unsigned short* csr_f = (unsigned short*)alloc((size_t)N * CAP * 2);
    int2*  ovf     = (int2*)alloc((size_t)4096 * 8);
    unsigned short* W1s = (unsigned short*)alloc((size_t)KT1 * 512 * 8 * 2);
    unsigned short* h   = (unsigned short*)alloc((size_t)N * HID * 2);
    float* h2s     = (float*)alloc((size_t)N * 8 * 4);

    // zero cnt + ovf_cnt (contiguous allocations)
    (void)hipMemsetAsync(cnt, 0, ((char*)ovf_cnt - (char*)cnt) + 256, stream);
    prep_w1<<<(KT1 * 512 + 511) / 512, 512, 0, stream>>>(W1, W1s);
    gemm_fill<<<GB + FB, 512, 0, stream>>>(x, W1s, h, N, src, dst, E,
                                           cnt, csr_f, ovf_cnt, ovf, GB);
    agg1<<<(N + 3) / 4, 256, 0, stream>>>(h, cnt, csr_f, b1, W2, ovf_cnt, ovf, h2s, N);
    agg2<<<(N + 7) / 8, 256, 0, stream>>>(h2s, cnt, csr_f, b2, ovf_cnt, ovf, out, N);
}